// Round 6
// baseline (169.332 us; speedup 1.0000x reference)
//
#include <hip/hip_runtime.h>
#include <math.h>

#define EPSF 1e-12f
#define ATT_NORM_F 4.0f
#define H_DIM 8
#define C_DIM 16
#define N_NODES 100000

typedef float v4f __attribute__((ext_vector_type(4)));

// ---------------------------------------------------------------------------
// Zero the seg table.
// ---------------------------------------------------------------------------
__global__ __launch_bounds__(256) void lip_zero(unsigned* __restrict__ p, int n)
{
    int i = blockIdx.x * 256 + threadIdx.x;
    if (i < n) p[i] = 0u;
}

// ---------------------------------------------------------------------------
// Pass 1 (merged, grid-stride): norm_x[r] = sum_c x[r,c]^2 ; guarded
// atomicMax into seg.
// 4 lanes per row -> each wave load covers 1 KB contiguous. x streamed nt.
// Test-before-atomic: plain cached load of seg, fire RMW only if s > cached.
// Stale cached values are <= the committed max (monotone), so skipping is
// safe; staleness only causes extra atomics, never missed updates.
// ---------------------------------------------------------------------------
__global__ __launch_bounds__(256) void lip_pass1(
    const float* __restrict__ x, const int* __restrict__ index,
    float* __restrict__ norm_x, unsigned int* __restrict__ seg, int total /*rows*4*/)
{
    const int stride = gridDim.x * 256;
    const int s0 = blockIdx.x * 256 + threadIdx.x;
    const int lane = s0 & 3;                 // stride % 4 == 0 -> constant
    const v4f* x4 = (const v4f*)x;

    #pragma unroll 8
    for (int s = s0; s < total; s += stride) {
        v4f v = __builtin_nontemporal_load(&x4[s]);
        float sum = v.x * v.x + v.y * v.y + v.z * v.z + v.w * v.w;
        sum += __shfl_xor(sum, 1);
        sum += __shfl_xor(sum, 2);
        if (lane == 0) {
            int r = s >> 2;
            __builtin_nontemporal_store(sum, &norm_x[r]);
            int e = r >> 3;
            int h = r & 7;
            unsigned* addr = &seg[(size_t)index[e] * H_DIM + h];
            unsigned bits = __float_as_uint(sum);   // sum >= 0: monotone bits
            if (bits > *addr)                       // cached test (stale-safe)
                atomicMax(addr, bits);
        }
    }
}

// ---------------------------------------------------------------------------
// Pass 2: out = alpha / (natt * sqrt(seg[idx] + norm_x) + eps)
// One thread per 4 heads (float4). seg gathers are cache-resident.
// ---------------------------------------------------------------------------
__global__ __launch_bounds__(256) void lip_pass2(
    const float* __restrict__ norm_x, const float* __restrict__ alpha,
    const int* __restrict__ index, const unsigned int* __restrict__ seg,
    const float* __restrict__ att_l, const float* __restrict__ att_r,
    float* __restrict__ out, int total)   // total = E*2
{
    __shared__ float s_natt[H_DIM];
    int t = threadIdx.x;
    if (t < H_DIM) {
        float s = 0.f;
        #pragma unroll
        for (int c = 0; c < C_DIM; ++c) {
            float l = att_l[t * C_DIM + c];
            float r = att_r[t * C_DIM + c];
            s += l * l + r * r;
        }
        s_natt[t] = ATT_NORM_F * sqrtf(s);
    }
    __syncthreads();

    const int stride = gridDim.x * 256;
    const v4f* nx4 = (const v4f*)norm_x;
    const v4f* al4 = (const v4f*)alpha;
    const v4f* sg4 = (const v4f*)seg;       // bits are non-negative floats
    v4f* out4 = (v4f*)out;

    #pragma unroll 4
    for (int tid = blockIdx.x * 256 + t; tid < total; tid += stride) {
        int e    = tid >> 1;
        int half = tid & 1;
        int idx  = index[e];

        v4f nx = nx4[tid];                               // L3-warm
        v4f al = __builtin_nontemporal_load(&al4[tid]);  // cold stream
        v4f sg = sg4[(size_t)idx * 2 + half];            // cached gather

        int h0 = half * 4;
        v4f o;
        o.x = al.x / (s_natt[h0 + 0] * sqrtf(sg.x + nx.x) + EPSF);
        o.y = al.y / (s_natt[h0 + 1] * sqrtf(sg.y + nx.y) + EPSF);
        o.z = al.z / (s_natt[h0 + 2] * sqrtf(sg.z + nx.z) + EPSF);
        o.w = al.w / (s_natt[h0 + 3] * sqrtf(sg.w + nx.w) + EPSF);
        __builtin_nontemporal_store(o, &out4[tid]);
    }
}

// ---------------------------------------------------------------------------
// Fallbacks (ws too small): merged pass1 w/o norm_x + recompute pass2.
// ---------------------------------------------------------------------------
__global__ __launch_bounds__(256) void lip_pass1_merged(
    const float* __restrict__ x, const int* __restrict__ index,
    unsigned int* __restrict__ seg, int total /*rows*4*/)
{
    const int stride = gridDim.x * 256;
    const int s0 = blockIdx.x * 256 + threadIdx.x;
    const int lane = s0 & 3;
    const v4f* x4 = (const v4f*)x;
    #pragma unroll 4
    for (int s = s0; s < total; s += stride) {
        v4f v = __builtin_nontemporal_load(&x4[s]);
        float sum = v.x * v.x + v.y * v.y + v.z * v.z + v.w * v.w;
        sum += __shfl_xor(sum, 1);
        sum += __shfl_xor(sum, 2);
        if (lane == 0) {
            int r = s >> 2;
            int e = r >> 3, h = r & 7;
            unsigned* addr = &seg[(size_t)index[e] * H_DIM + h];
            unsigned bits = __float_as_uint(sum);
            if (bits > *addr)
                atomicMax(addr, bits);
        }
    }
}

__global__ __launch_bounds__(256) void lip_pass2_recompute(
    const float* __restrict__ x, const float* __restrict__ alpha,
    const int* __restrict__ index, const unsigned int* __restrict__ seg,
    const float* __restrict__ att_l, const float* __restrict__ att_r,
    float* __restrict__ out, int rows)
{
    __shared__ float s_natt[H_DIM];
    int t = threadIdx.x;
    if (t < H_DIM) {
        float s = 0.f;
        #pragma unroll
        for (int c = 0; c < C_DIM; ++c) {
            float l = att_l[t * C_DIM + c];
            float r = att_r[t * C_DIM + c];
            s += l * l + r * r;
        }
        s_natt[t] = ATT_NORM_F * sqrtf(s);
    }
    __syncthreads();

    int r = blockIdx.x * blockDim.x + t;
    if (r >= rows) return;

    const float4* x4 = (const float4*)x;
    float s = 0.f;
    #pragma unroll
    for (int q = 0; q < 4; ++q) {
        float4 v = x4[(size_t)r * 4 + q];
        s += v.x * v.x + v.y * v.y + v.z * v.z + v.w * v.w;
    }
    int e = r >> 3;
    int h = r & 7;
    float sg = __uint_as_float(seg[(size_t)index[e] * H_DIM + h]);
    out[r] = alpha[r] / (s_natt[h] * sqrtf(sg + s) + EPSF);
}

extern "C" void kernel_launch(void* const* d_in, const int* in_sizes, int n_in,
                              void* d_out, int out_size, void* d_ws, size_t ws_size,
                              hipStream_t stream) {
    const float* x     = (const float*)d_in[0];
    const float* att_l = (const float*)d_in[1];
    const float* att_r = (const float*)d_in[2];
    const float* alpha = (const float*)d_in[3];
    const int*   index = (const int*)d_in[4];

    const int E    = in_sizes[4];
    const int rows = E * H_DIM;

    const int seg_words = N_NODES * H_DIM;        // 800000 = 3.2 MB
    size_t seg_pad = ((size_t)seg_words * 4 + 255) / 256 * 256;
    size_t need    = seg_pad + (size_t)rows * sizeof(float);

    unsigned* seg = (unsigned*)d_ws;
    lip_zero<<<(seg_words + 255) / 256, 256, 0, stream>>>(seg, seg_words);

    if (ws_size >= need) {
        float* norm_x = (float*)((char*)d_ws + seg_pad);
        lip_pass1<<<2048, 256, 0, stream>>>(x, index, norm_x, seg, rows * 4);
        lip_pass2<<<2048, 256, 0, stream>>>(
            norm_x, alpha, index, seg, att_l, att_r, (float*)d_out, E * 2);
    } else {
        lip_pass1_merged<<<2048, 256, 0, stream>>>(x, index, seg, rows * 4);
        lip_pass2_recompute<<<(rows + 255) / 256, 256, 0, stream>>>(
            x, alpha, index, seg, att_l, att_r, (float*)d_out, rows);
    }
}

// Round 7
// 160.496 us; speedup vs baseline: 1.0551x; 1.0551x over previous
//
#include <hip/hip_runtime.h>
#include <math.h>

#define EPSF 1e-12f
#define ATT_NORM_F 4.0f
#define H_DIM 8
#define C_DIM 16
#define N_NODES 100000
#define SEG_WORDS (N_NODES * H_DIM)   // 800000 words = 3.2 MB
#define NXCD 8

typedef float v4f __attribute__((ext_vector_type(4)));
typedef unsigned v4u __attribute__((ext_vector_type(4)));

// ---------------------------------------------------------------------------
// Zero n words.
// ---------------------------------------------------------------------------
__global__ __launch_bounds__(256) void lip_zero(unsigned* __restrict__ p, int n)
{
    int i = blockIdx.x * 256 + threadIdx.x;
    if (i < n) p[i] = 0u;
}

// ---------------------------------------------------------------------------
// Pass 1 (grid-stride): norm_x[r] = sum_c x[r,c]^2 ; scatter-max into the
// issuing XCD's PRIVATE table with WORKGROUP-scope atomics.
// All writers of part[X] run on XCD X (physical ID via s_getreg XCC_ID), so
// the atomic only needs to be atomic within one L2 -> workgroup scope
// suffices and executes at the local, table-resident L2 instead of the
// cross-XCD coherence point. Dispatch-end L2 writeback publishes partials.
// ---------------------------------------------------------------------------
__global__ __launch_bounds__(256) void lip_pass1(
    const float* __restrict__ x, const int* __restrict__ index,
    float* __restrict__ norm_x, unsigned* __restrict__ part, int total /*rows*4*/)
{
    unsigned xcd;
    asm volatile("s_getreg_b32 %0, hwreg(HW_REG_XCC_ID)" : "=s"(xcd));
    unsigned* __restrict__ table = part + (size_t)(xcd & 7) * SEG_WORDS;

    const int stride = gridDim.x * 256;
    const int s0 = blockIdx.x * 256 + threadIdx.x;
    const int lane = s0 & 3;                 // stride % 4 == 0 -> constant
    const v4f* x4 = (const v4f*)x;

    #pragma unroll 4
    for (int s = s0; s < total; s += stride) {
        v4f v = __builtin_nontemporal_load(&x4[s]);
        float sum = v.x * v.x + v.y * v.y + v.z * v.z + v.w * v.w;
        sum += __shfl_xor(sum, 1);
        sum += __shfl_xor(sum, 2);
        if (lane == 0) {
            int r = s >> 2;
            __builtin_nontemporal_store(sum, &norm_x[r]);
            int e = r >> 3;
            int h = r & 7;
            // sum >= 0: float bits monotone under unsigned max
            __hip_atomic_fetch_max(&table[index[e] * H_DIM + h],
                                   __float_as_uint(sum),
                                   __ATOMIC_RELAXED,
                                   __HIP_MEMORY_SCOPE_WORKGROUP);
        }
    }
}

// ---------------------------------------------------------------------------
// Merge: seg[i] = max over the 8 per-XCD partials. Pure streaming, ~29 MB.
// One thread per 4 words.
// ---------------------------------------------------------------------------
__global__ __launch_bounds__(256) void lip_merge(
    const unsigned* __restrict__ part, unsigned* __restrict__ seg, int quads)
{
    int q = blockIdx.x * 256 + threadIdx.x;
    if (q >= quads) return;
    const v4u* p4 = (const v4u*)part;
    const int tq = SEG_WORDS / 4;
    v4u m = p4[q];
    #pragma unroll
    for (int xx = 1; xx < NXCD; ++xx) {
        v4u w = p4[(size_t)xx * tq + q];
        m.x = m.x > w.x ? m.x : w.x;
        m.y = m.y > w.y ? m.y : w.y;
        m.z = m.z > w.z ? m.z : w.z;
        m.w = m.w > w.w ? m.w : w.w;
    }
    ((v4u*)seg)[q] = m;
}

// ---------------------------------------------------------------------------
// Pass 2: out = alpha / (natt * sqrt(seg[idx] + norm_x) + eps)
// One thread per 4 heads (float4). seg gathers are cache-resident.
// ---------------------------------------------------------------------------
__global__ __launch_bounds__(256) void lip_pass2(
    const float* __restrict__ norm_x, const float* __restrict__ alpha,
    const int* __restrict__ index, const unsigned int* __restrict__ seg,
    const float* __restrict__ att_l, const float* __restrict__ att_r,
    float* __restrict__ out, int total)   // total = E*2
{
    __shared__ float s_natt[H_DIM];
    int t = threadIdx.x;
    if (t < H_DIM) {
        float s = 0.f;
        #pragma unroll
        for (int c = 0; c < C_DIM; ++c) {
            float l = att_l[t * C_DIM + c];
            float r = att_r[t * C_DIM + c];
            s += l * l + r * r;
        }
        s_natt[t] = ATT_NORM_F * sqrtf(s);
    }
    __syncthreads();

    const int stride = gridDim.x * 256;
    const v4f* nx4 = (const v4f*)norm_x;
    const v4f* al4 = (const v4f*)alpha;
    const v4f* sg4 = (const v4f*)seg;       // bits are non-negative floats
    v4f* out4 = (v4f*)out;

    #pragma unroll 4
    for (int tid = blockIdx.x * 256 + t; tid < total; tid += stride) {
        int e    = tid >> 1;
        int half = tid & 1;
        int idx  = index[e];

        v4f nx = nx4[tid];
        v4f al = __builtin_nontemporal_load(&al4[tid]);  // cold stream
        v4f sg = sg4[(size_t)idx * 2 + half];            // cached gather

        int h0 = half * 4;
        v4f o;
        o.x = al.x / (s_natt[h0 + 0] * sqrtf(sg.x + nx.x) + EPSF);
        o.y = al.y / (s_natt[h0 + 1] * sqrtf(sg.y + nx.y) + EPSF);
        o.z = al.z / (s_natt[h0 + 2] * sqrtf(sg.z + nx.z) + EPSF);
        o.w = al.w / (s_natt[h0 + 3] * sqrtf(sg.w + nx.w) + EPSF);
        __builtin_nontemporal_store(o, &out4[tid]);
    }
}

// ---------------------------------------------------------------------------
// Fallbacks (ws too small): single-table device-scope path (R4 behavior).
// ---------------------------------------------------------------------------
__global__ __launch_bounds__(256) void lip_pass1_single(
    const float* __restrict__ x, const int* __restrict__ index,
    unsigned int* __restrict__ seg, int total /*rows*4*/)
{
    const int stride = gridDim.x * 256;
    const int s0 = blockIdx.x * 256 + threadIdx.x;
    const int lane = s0 & 3;
    const v4f* x4 = (const v4f*)x;
    #pragma unroll 4
    for (int s = s0; s < total; s += stride) {
        v4f v = __builtin_nontemporal_load(&x4[s]);
        float sum = v.x * v.x + v.y * v.y + v.z * v.z + v.w * v.w;
        sum += __shfl_xor(sum, 1);
        sum += __shfl_xor(sum, 2);
        if (lane == 0) {
            int r = s >> 2;
            int e = r >> 3, h = r & 7;
            atomicMax(&seg[(size_t)index[e] * H_DIM + h], __float_as_uint(sum));
        }
    }
}

__global__ __launch_bounds__(256) void lip_pass2_recompute(
    const float* __restrict__ x, const float* __restrict__ alpha,
    const int* __restrict__ index, const unsigned int* __restrict__ seg,
    const float* __restrict__ att_l, const float* __restrict__ att_r,
    float* __restrict__ out, int rows)
{
    __shared__ float s_natt[H_DIM];
    int t = threadIdx.x;
    if (t < H_DIM) {
        float s = 0.f;
        #pragma unroll
        for (int c = 0; c < C_DIM; ++c) {
            float l = att_l[t * C_DIM + c];
            float r = att_r[t * C_DIM + c];
            s += l * l + r * r;
        }
        s_natt[t] = ATT_NORM_F * sqrtf(s);
    }
    __syncthreads();

    int r = blockIdx.x * blockDim.x + t;
    if (r >= rows) return;

    const float4* x4 = (const float4*)x;
    float s = 0.f;
    #pragma unroll
    for (int q = 0; q < 4; ++q) {
        float4 v = x4[(size_t)r * 4 + q];
        s += v.x * v.x + v.y * v.y + v.z * v.z + v.w * v.w;
    }
    int e = r >> 3;
    int h = r & 7;
    float sg = __uint_as_float(seg[(size_t)index[e] * H_DIM + h]);
    out[r] = alpha[r] / (s_natt[h] * sqrtf(sg + s) + EPSF);
}

extern "C" void kernel_launch(void* const* d_in, const int* in_sizes, int n_in,
                              void* d_out, int out_size, void* d_ws, size_t ws_size,
                              hipStream_t stream) {
    const float* x     = (const float*)d_in[0];
    const float* att_l = (const float*)d_in[1];
    const float* att_r = (const float*)d_in[2];
    const float* alpha = (const float*)d_in[3];
    const int*   index = (const int*)d_in[4];

    const int E    = in_sizes[4];
    const int rows = E * H_DIM;

    // ws layout: part[8][SEG_WORDS] | seg[SEG_WORDS] | norm_x[rows]
    size_t part_bytes = (size_t)NXCD * SEG_WORDS * 4;
    size_t seg_off    = (part_bytes + 255) / 256 * 256;
    size_t nx_off     = (seg_off + (size_t)SEG_WORDS * 4 + 255) / 256 * 256;
    size_t need       = nx_off + (size_t)rows * 4;

    if (ws_size >= need) {
        unsigned* part   = (unsigned*)d_ws;
        unsigned* seg    = (unsigned*)((char*)d_ws + seg_off);
        float*    norm_x = (float*)((char*)d_ws + nx_off);

        int zwords = NXCD * SEG_WORDS;
        lip_zero<<<(zwords + 255) / 256, 256, 0, stream>>>(part, zwords);
        lip_pass1<<<2048, 256, 0, stream>>>(x, index, norm_x, part, rows * 4);
        int quads = SEG_WORDS / 4;
        lip_merge<<<(quads + 255) / 256, 256, 0, stream>>>(part, seg, quads);
        lip_pass2<<<2048, 256, 0, stream>>>(
            norm_x, alpha, index, seg, att_l, att_r, (float*)d_out, E * 2);
    } else {
        unsigned* seg = (unsigned*)d_ws;
        lip_zero<<<(SEG_WORDS + 255) / 256, 256, 0, stream>>>(seg, SEG_WORDS);
        lip_pass1_single<<<2048, 256, 0, stream>>>(x, index, seg, rows * 4);
        lip_pass2_recompute<<<(rows + 255) / 256, 256, 0, stream>>>(
            x, alpha, index, seg, att_l, att_r, (float*)d_out, rows);
    }
}